// Round 1
// baseline (135.803 us; speedup 1.0000x reference)
//
#include <hip/hip_runtime.h>
#include <math.h>

// GramVolumeCalculator: fused row-wise Gram determinant volume + sigmoid score.
// B=65536 rows, D=1024 fp32. One wave (64 lanes) per row, 4 waves/block.
// Normalization folded analytically into dot products (no normalized vectors
// materialized): n_i = s_ii/r_i^2, d_ij = s_ij/(r_i r_j), r_i = max(sqrt(s_ii),1e-12).

#define WAVES_PER_BLOCK 4
#define BLOCK (WAVES_PER_BLOCK * 64)
#define DIM 1024

__global__ __launch_bounds__(BLOCK) void gramvol_kernel(
    const float* __restrict__ f1,
    const float* __restrict__ f2,
    const float* __restrict__ f3,
    float* __restrict__ out,   // [2*B]: volume[0..B), score[B..2B)
    int B)
{
    const int lane = threadIdx.x & 63;
    const int wid  = threadIdx.x >> 6;
    const int row  = blockIdx.x * WAVES_PER_BLOCK + wid;
    if (row >= B) return;

    const size_t base = (size_t)row * DIM;
    const float4* __restrict__ p1 = (const float4*)(f1 + base);
    const float4* __restrict__ p2 = (const float4*)(f2 + base);
    const float4* __restrict__ p3 = (const float4*)(f3 + base);

    float s11 = 0.f, s22 = 0.f, s33 = 0.f;
    float s12 = 0.f, s13 = 0.f, s23 = 0.f;

    // 256 float4 chunks per row; lane i takes chunks {i, 64+i, 128+i, 192+i}.
    // Each load instruction: 64 lanes x 16B contiguous = perfectly coalesced.
    #pragma unroll
    for (int c = 0; c < DIM / 4 / 64; ++c) {
        const int idx = c * 64 + lane;
        float4 a = p1[idx];
        float4 b = p2[idx];
        float4 d = p3[idx];
        s11 = fmaf(a.x, a.x, fmaf(a.y, a.y, fmaf(a.z, a.z, fmaf(a.w, a.w, s11))));
        s22 = fmaf(b.x, b.x, fmaf(b.y, b.y, fmaf(b.z, b.z, fmaf(b.w, b.w, s22))));
        s33 = fmaf(d.x, d.x, fmaf(d.y, d.y, fmaf(d.z, d.z, fmaf(d.w, d.w, s33))));
        s12 = fmaf(a.x, b.x, fmaf(a.y, b.y, fmaf(a.z, b.z, fmaf(a.w, b.w, s12))));
        s13 = fmaf(a.x, d.x, fmaf(a.y, d.y, fmaf(a.z, d.z, fmaf(a.w, d.w, s13))));
        s23 = fmaf(b.x, d.x, fmaf(b.y, d.y, fmaf(b.z, d.z, fmaf(b.w, d.w, s23))));
    }

    // Wave-wide butterfly reduction (64 lanes).
    #pragma unroll
    for (int off = 32; off >= 1; off >>= 1) {
        s11 += __shfl_xor(s11, off);
        s22 += __shfl_xor(s22, off);
        s33 += __shfl_xor(s33, off);
        s12 += __shfl_xor(s12, off);
        s13 += __shfl_xor(s13, off);
        s23 += __shfl_xor(s23, off);
    }

    if (lane == 0) {
        const float r1 = fmaxf(sqrtf(s11), 1e-12f);
        const float r2 = fmaxf(sqrtf(s22), 1e-12f);
        const float r3 = fmaxf(sqrtf(s33), 1e-12f);
        const float i1 = 1.0f / r1, i2 = 1.0f / r2, i3 = 1.0f / r3;
        const float n1 = s11 * i1 * i1;
        const float n2 = s22 * i2 * i2;
        const float n3 = s33 * i3 * i3;
        const float d12 = s12 * i1 * i2;
        const float d13 = s13 * i1 * i3;
        const float d23 = s23 * i2 * i3;
        float det = n1 * n2 * n3 + 2.0f * d12 * d13 * d23
                  - n1 * d23 * d23 - n2 * d13 * d13 - n3 * d12 * d12;
        det = fmaxf(det, 1e-8f);
        const float vol = sqrtf(det);
        // sigmoid(-vol*10 + 5)
        const float score = 1.0f / (1.0f + __expf(vol * 10.0f - 5.0f));
        out[row]     = vol;
        out[B + row] = score;
    }
}

extern "C" void kernel_launch(void* const* d_in, const int* in_sizes, int n_in,
                              void* d_out, int out_size, void* d_ws, size_t ws_size,
                              hipStream_t stream) {
    const float* f1 = (const float*)d_in[0];
    const float* f2 = (const float*)d_in[1];
    const float* f3 = (const float*)d_in[2];
    float* out = (float*)d_out;
    const int B = in_sizes[0] / DIM;  // 65536

    dim3 grid((B + WAVES_PER_BLOCK - 1) / WAVES_PER_BLOCK);
    hipLaunchKernelGGL(gramvol_kernel, grid, dim3(BLOCK), 0, stream,
                       f1, f2, f3, out, B);
}